// Round 4
// baseline (589.639 us; speedup 1.0000x reference)
//
#include <hip/hip_runtime.h>
#include <hip/hip_bf16.h>
#include <math.h>

// LGNGuard: 3-layer guarded LightGCN propagation + sigmoid(U @ I^T) scoring.
// CSR by src row; cos computed once per undirected edge (cos is symmetric);
// prune+EMA fused into SpMM. D=64. Quad layout: 4 lanes/row, 16 dims/lane.

#define DD 64

// ================= CSR build =================

__global__ __launch_bounds__(256) void hist_k(const int* __restrict__ src,
                                              int* __restrict__ deg, int E) {
    int e = blockIdx.x * blockDim.x + threadIdx.x;
    if (e < E) atomicAdd(&deg[src[e]], 1);
}

__global__ __launch_bounds__(256) void scan1_k(const int* __restrict__ in,
                                               int* __restrict__ out,
                                               int* __restrict__ partial, int M) {
    __shared__ int sh[256];
    int base = blockIdx.x * 1024;
    int t = threadIdx.x;
    int i0 = base + t * 4;
    int v0 = (i0 + 0 < M) ? in[i0 + 0] : 0;
    int v1 = (i0 + 1 < M) ? in[i0 + 1] : 0;
    int v2 = (i0 + 2 < M) ? in[i0 + 2] : 0;
    int v3 = (i0 + 3 < M) ? in[i0 + 3] : 0;
    int tsum = v0 + v1 + v2 + v3;
    sh[t] = tsum;
    __syncthreads();
    for (int off = 1; off < 256; off <<= 1) {
        int x = (t >= off) ? sh[t - off] : 0;
        __syncthreads();
        sh[t] += x;
        __syncthreads();
    }
    int texcl = sh[t] - tsum;
    if (i0 + 0 < M) out[i0 + 0] = texcl;
    if (i0 + 1 < M) out[i0 + 1] = texcl + v0;
    if (i0 + 2 < M) out[i0 + 2] = texcl + v0 + v1;
    if (i0 + 3 < M) out[i0 + 3] = texcl + v0 + v1 + v2;
    if (t == 255) partial[blockIdx.x] = sh[255];
}

__global__ __launch_bounds__(256) void scan2_k(int* __restrict__ partial, int nc) {
    __shared__ int sh[256];
    int t = threadIdx.x;
    int v = (t < nc) ? partial[t] : 0;
    sh[t] = v;
    __syncthreads();
    for (int off = 1; off < 256; off <<= 1) {
        int x = (t >= off) ? sh[t - off] : 0;
        __syncthreads();
        sh[t] += x;
        __syncthreads();
    }
    if (t < nc) partial[t] = sh[t] - v;
}

__global__ __launch_bounds__(256) void scan3_k(int* __restrict__ out,
                                               const int* __restrict__ partial, int M) {
    int i = blockIdx.x * blockDim.x + threadIdx.x;
    if (i < M) out[i] += partial[i >> 10];
}

// One thread per UNDIRECTED edge: scatter both directions.
// ent[pos] = {dst, adj_bits, cosidx(=user-CSR position of this edge), 0}
__global__ __launch_bounds__(256) void scatter_k(const int* __restrict__ src,
                                                 const int* __restrict__ dst,
                                                 const float* __restrict__ adj,
                                                 int* __restrict__ cursor,
                                                 int4* __restrict__ ent, int EH) {
    int e = blockIdx.x * blockDim.x + threadIdx.x;
    if (e >= EH) return;
    int u = src[e], i = dst[e];
    float a0 = adj[e], a1 = adj[e + EH];
    int posU = atomicAdd(&cursor[u], 1);
    int posI = atomicAdd(&cursor[i], 1);
    ent[posU] = make_int4(i, __float_as_int(a0), posU, 0);
    ent[posI] = make_int4(u, __float_as_int(a1), posU, 0);
}

// ================= per-layer =================

__global__ __launch_bounds__(256) void node_norms_k(const float* __restrict__ emb,
                                                    float* __restrict__ norms, int n) {
    int lane = threadIdx.x & 63;
    int wid  = (blockIdx.x * blockDim.x + threadIdx.x) >> 6;
    int nw   = (gridDim.x * blockDim.x) >> 6;
    for (int node = wid; node < n; node += nw) {
        float v = emb[(size_t)node * DD + lane];
        float s = v * v;
#pragma unroll
        for (int m = 32; m > 0; m >>= 1) s += __shfl_xor(s, m, 64);
        if (lane == 0) norms[node] = sqrtf(s);
    }
}

// cos + rowsums over USER rows only (each undirected edge once).
// User rowsum in-register; item rowsum via one scalar atomic per edge.
__global__ __launch_bounds__(256) void cos_row_k(const float* __restrict__ emb,
                                                 const float* __restrict__ norms,
                                                 const int* __restrict__ rp,
                                                 const int4* __restrict__ ent,
                                                 float* __restrict__ cosc,
                                                 float* __restrict__ rowsum, int NU) {
    int quad = (blockIdx.x * blockDim.x + threadIdx.x) >> 2;
    int l4   = threadIdx.x & 3;
    if (quad >= NU) return;
    int r  = quad;
    int p0 = rp[r], p1 = rp[r + 1];
    const float4* embv = (const float4*)emb;
    float4 A[4];
#pragma unroll
    for (int k = 0; k < 4; ++k) A[k] = embv[(size_t)r * 16 + k * 4 + l4];
    float nr = norms[r];
    float rs = 0.f;
    for (int p = p0; p < p1; ++p) {
        int d = ent[p].x;
        float dot = 0.f;
#pragma unroll
        for (int k = 0; k < 4; ++k) {
            float4 b = embv[(size_t)d * 16 + k * 4 + l4];
            dot += A[k].x * b.x + A[k].y * b.y + A[k].z * b.z + A[k].w * b.w;
        }
        dot += __shfl_xor(dot, 1, 64);
        dot += __shfl_xor(dot, 2, 64);
        float c = dot / fmaxf(nr * norms[d], 1e-8f);
        if (l4 == 0) {
            cosc[p] = c;
            atomicAdd(&rowsum[d], fabsf(c));
        }
        rs += fabsf(c);
    }
    if (l4 == 0) rowsum[r] = rs;
}

// Fused normalize + prune + memory EMA + SpMM. Row-based, no atomics.
// c  = cos / guard(rowsum[row]);  cr = cos / guard(rowsum[dst])  (cos symmetric)
__global__ __launch_bounds__(256) void spmm_fused_k(const float* __restrict__ emb,
                                                    const int* __restrict__ rp,
                                                    const int4* __restrict__ ent,
                                                    const float* __restrict__ cosc,
                                                    const float* __restrict__ rowsum,
                                                    const float* __restrict__ Wp,
                                                    const float* __restrict__ bp,
                                                    float* __restrict__ memc, int useAdj,
                                                    float* __restrict__ out, int N) {
    int quad = (blockIdx.x * blockDim.x + threadIdx.x) >> 2;
    int l4   = threadIdx.x & 3;
    if (quad >= N) return;
    int r  = quad;
    int p0 = rp[r], p1 = rp[r + 1];
    float w0 = Wp[0], w1 = Wp[1], bb = bp[0];
    float rs  = rowsum[r];
    float rsg = rs > 0.f ? rs : 1.f;
    const float4* embv = (const float4*)emb;
    float4 acc[4];
#pragma unroll
    for (int k = 0; k < 4; ++k) acc[k] = make_float4(0.f, 0.f, 0.f, 0.f);
    for (int p = p0; p < p1; ++p) {
        int4 t = ent[p];
        int d = t.x;
        float a  = __int_as_float(t.y);
        float cv = cosc[t.z];
        float rd  = rowsum[d];
        float rdg = rd > 0.f ? rd : 1.f;
        float c  = cv / rsg;
        float cr = cv / rdg;
        float z  = w0 * c + w1 * cr + bb;
        float kept = (z > 0.f) ? c : 0.f;
        float mprev = useAdj ? a : memc[p];
        float m = 0.5f * mprev + 0.5f * kept;
        if (l4 == 0) memc[p] = m;
        float g = m * a;
#pragma unroll
        for (int k = 0; k < 4; ++k) {
            float4 b = embv[(size_t)d * 16 + k * 4 + l4];
            acc[k].x += g * b.x;
            acc[k].y += g * b.y;
            acc[k].z += g * b.z;
            acc[k].w += g * b.w;
        }
    }
    float4* outv = (float4*)out;
#pragma unroll
    for (int k = 0; k < 4; ++k) outv[(size_t)r * 16 + k * 4 + l4] = acc[k];
}

// ================= selected-row accumulation + scoring =================

__global__ __launch_bounds__(256) void acc_update_k(const float* __restrict__ emb,
                                                    const int* __restrict__ users,
                                                    const int* __restrict__ items,
                                                    float* __restrict__ acc,
                                                    int BU, int BI, int NU, int init) {
    int tid = blockIdx.x * blockDim.x + threadIdx.x;
    int total = (BU + BI) * DD;
    if (tid >= total) return;
    int row = tid >> 6, d = tid & 63;
    int node = (row < BU) ? users[row] : (NU + items[row - BU]);
    float v = emb[(size_t)node * DD + d];
    if (init) acc[tid] = v;
    else      acc[tid] += v;
}

__global__ __launch_bounds__(256) void final_gemm_k(const float* __restrict__ acc,
                                                    float* __restrict__ out,
                                                    int BU, int BI) {
    __shared__ float Us[16][64];
    __shared__ float Is[16][65];
    int tx = threadIdx.x & 15, ty = threadIdx.x >> 4;
    int i0 = blockIdx.y * 16, j0 = blockIdx.x * 16;
    for (int t = threadIdx.x; t < 16 * 64; t += 256) {
        int r = t >> 6, k = t & 63;
        Us[r][k] = acc[(size_t)(i0 + r) * DD + k];
        Is[r][k] = acc[(size_t)(BU + j0 + r) * DD + k];
    }
    __syncthreads();
    float sum = 0.f;
#pragma unroll
    for (int k = 0; k < 64; ++k) sum += Us[ty][k] * Is[tx][k];
    float z = sum * 0.0625f;
    out[(size_t)(i0 + ty) * BI + (j0 + tx)] = 1.f / (1.f + expf(-z));
}

// ================= launch =================

extern "C" void kernel_launch(void* const* d_in, const int* in_sizes, int n_in,
                              void* d_out, int out_size, void* d_ws, size_t ws_size,
                              hipStream_t stream) {
    const int*   users    = (const int*)d_in[0];
    const int*   items    = (const int*)d_in[1];
    const float* user_emb = (const float*)d_in[2];
    const float* item_emb = (const float*)d_in[3];
    const float* Wp       = (const float*)d_in[4];
    const float* bp       = (const float*)d_in[5];
    const int*   src      = (const int*)d_in[6];
    const int*   dst      = (const int*)d_in[7];
    const float* adj      = (const float*)d_in[9];

    int BU = in_sizes[0];
    int BI = in_sizes[1];
    int NU = in_sizes[2] / DD;
    int NI = in_sizes[3] / DD;
    int Nn = NU + NI;
    int E  = in_sizes[6];
    int EH = E / 2;
    int M  = Nn + 1;
    int Mp = (M + 3) & ~3;  // padded to keep 16B alignment downstream

    // ---- workspace layout (4B units; ent first for 16B alignment) ----
    int*   ent_i  = (int*)d_ws;                        // E*4
    float* embA   = (float*)(ent_i + (size_t)E * 4);   // Nn*64
    float* embB   = embA + (size_t)Nn * DD;            // Nn*64
    float* norms  = embB + (size_t)Nn * DD;            // Nn
    float* rowsum = norms + Nn;                        // Nn
    float* cosc   = rowsum + Nn;                       // EH
    float* memc   = cosc + EH;                         // E
    float* acc    = memc + E;                          // (BU+BI)*64
    int*   deg    = (int*)(acc + (size_t)(BU + BI) * DD);  // Mp
    int*   rp     = deg + Mp;                          // Mp
    int*   cursor = rp + Mp;                           // Nn
    int*   partial= cursor + Nn;                       // 256
    int4*  ent    = (int4*)ent_i;

    int eb  = (E + 255) / 256;
    int ehb = (EH + 255) / 256;
    int nc  = (M + 1023) / 1024;

    // ---- CSR build ----
    hipMemsetAsync(deg, 0, sizeof(int) * (size_t)M, stream);
    hist_k<<<eb, 256, 0, stream>>>(src, deg, E);
    scan1_k<<<nc, 256, 0, stream>>>(deg, rp, partial, M);
    scan2_k<<<1, 256, 0, stream>>>(partial, nc);
    scan3_k<<<(M + 255) / 256, 256, 0, stream>>>(rp, partial, M);
    hipMemcpyAsync(cursor, rp, sizeof(int) * (size_t)Nn, hipMemcpyDeviceToDevice, stream);
    scatter_k<<<ehb, 256, 0, stream>>>(src, dst, adj, cursor, ent, EH);

    // ---- emb0 = concat(user_emb, item_emb) ----
    hipMemcpyAsync(embA, user_emb, sizeof(float) * (size_t)NU * DD,
                   hipMemcpyDeviceToDevice, stream);
    hipMemcpyAsync(embA + (size_t)NU * DD, item_emb, sizeof(float) * (size_t)NI * DD,
                   hipMemcpyDeviceToDevice, stream);

    int accThreads = (BU + BI) * DD;
    acc_update_k<<<(accThreads + 255) / 256, 256, 0, stream>>>(embA, users, items, acc,
                                                               BU, BI, NU, 1);

    int rowBlocksU = (4 * NU + 255) / 256;
    int rowBlocksN = (4 * Nn + 255) / 256;
    float* cur = embA;
    float* nxt = embB;
    for (int layer = 0; layer < 3; ++layer) {
        hipMemsetAsync(rowsum, 0, sizeof(float) * (size_t)Nn, stream);
        node_norms_k<<<1024, 256, 0, stream>>>(cur, norms, Nn);
        cos_row_k<<<rowBlocksU, 256, 0, stream>>>(cur, norms, rp, ent, cosc, rowsum, NU);
        spmm_fused_k<<<rowBlocksN, 256, 0, stream>>>(cur, rp, ent, cosc, rowsum,
                                                     Wp, bp, memc, layer == 0 ? 1 : 0,
                                                     nxt, Nn);
        acc_update_k<<<(accThreads + 255) / 256, 256, 0, stream>>>(nxt, users, items, acc,
                                                                   BU, BI, NU, 0);
        float* t = cur; cur = nxt; nxt = t;
    }

    dim3 grid(BI / 16, BU / 16);
    final_gemm_k<<<grid, 256, 0, stream>>>(acc, (float*)d_out, BU, BI);
}

// Round 5
// 464.672 us; speedup vs baseline: 1.2689x; 1.2689x over previous
//
#include <hip/hip_runtime.h>
#include <hip/hip_bf16.h>
#include <math.h>

// LGNGuard: 3-layer guarded LightGCN propagation + sigmoid(U @ I^T) scoring.
// CSR by src row (atomic-free scatter via hist-rank); cos computed once per
// undirected edge (symmetric); prune+EMA fused into SpMM; final layer's SpMM
// computed only for the 4096 selected rows. D=64. Quad layout: 4 lanes/row.

#define DD 64

// ================= CSR build =================

// histogram + per-edge within-row rank (atomic's return value)
__global__ __launch_bounds__(256) void hist_k(const int* __restrict__ src,
                                              int* __restrict__ deg,
                                              int* __restrict__ rank, int E) {
    int e = blockIdx.x * blockDim.x + threadIdx.x;
    if (e < E) rank[e] = atomicAdd(&deg[src[e]], 1);
}

__global__ __launch_bounds__(256) void scan1_k(const int* __restrict__ in,
                                               int* __restrict__ out,
                                               int* __restrict__ partial, int M) {
    __shared__ int sh[256];
    int base = blockIdx.x * 1024;
    int t = threadIdx.x;
    int i0 = base + t * 4;
    int v0 = (i0 + 0 < M) ? in[i0 + 0] : 0;
    int v1 = (i0 + 1 < M) ? in[i0 + 1] : 0;
    int v2 = (i0 + 2 < M) ? in[i0 + 2] : 0;
    int v3 = (i0 + 3 < M) ? in[i0 + 3] : 0;
    int tsum = v0 + v1 + v2 + v3;
    sh[t] = tsum;
    __syncthreads();
    for (int off = 1; off < 256; off <<= 1) {
        int x = (t >= off) ? sh[t - off] : 0;
        __syncthreads();
        sh[t] += x;
        __syncthreads();
    }
    int texcl = sh[t] - tsum;
    if (i0 + 0 < M) out[i0 + 0] = texcl;
    if (i0 + 1 < M) out[i0 + 1] = texcl + v0;
    if (i0 + 2 < M) out[i0 + 2] = texcl + v0 + v1;
    if (i0 + 3 < M) out[i0 + 3] = texcl + v0 + v1 + v2;
    if (t == 255) partial[blockIdx.x] = sh[255];
}

__global__ __launch_bounds__(256) void scan2_k(int* __restrict__ partial, int nc) {
    __shared__ int sh[256];
    int t = threadIdx.x;
    int v = (t < nc) ? partial[t] : 0;
    sh[t] = v;
    __syncthreads();
    for (int off = 1; off < 256; off <<= 1) {
        int x = (t >= off) ? sh[t - off] : 0;
        __syncthreads();
        sh[t] += x;
        __syncthreads();
    }
    if (t < nc) partial[t] = sh[t] - v;
}

__global__ __launch_bounds__(256) void scan3_k(int* __restrict__ out,
                                               const int* __restrict__ partial, int M) {
    int i = blockIdx.x * blockDim.x + threadIdx.x;
    if (i < M) out[i] += partial[i >> 10];
}

// One thread per UNDIRECTED edge: both directions, NO atomics.
// ent[pos] = {dst, adj_bits, cosidx(=user-CSR pos of the undirected edge), 0}
__global__ __launch_bounds__(256) void scatter_k(const int* __restrict__ src,
                                                 const int* __restrict__ dst,
                                                 const float* __restrict__ adj,
                                                 const int* __restrict__ rp,
                                                 const int* __restrict__ rank,
                                                 int4* __restrict__ ent, int EH) {
    int e = blockIdx.x * blockDim.x + threadIdx.x;
    if (e >= EH) return;
    int u = src[e], i = dst[e];
    int ab = __float_as_int(adj[e]);       // adj is symmetric by construction
    int posU = rp[u] + rank[e];
    int posI = rp[i] + rank[e + EH];
    ent[posU] = make_int4(i, ab, posU, 0);
    ent[posI] = make_int4(u, ab, posU, 0);
}

// ================= per-layer =================

// quad per node: 16 dims/lane as 4x float4, 2-shfl reduce
__global__ __launch_bounds__(256) void node_norms_k(const float* __restrict__ emb,
                                                    float* __restrict__ norms, int n) {
    int quad = (blockIdx.x * blockDim.x + threadIdx.x) >> 2;
    int l4   = threadIdx.x & 3;
    if (quad >= n) return;
    const float4* embv = (const float4*)emb;
    float s = 0.f;
#pragma unroll
    for (int k = 0; k < 4; ++k) {
        float4 v = embv[(size_t)quad * 16 + k * 4 + l4];
        s += v.x * v.x + v.y * v.y + v.z * v.z + v.w * v.w;
    }
    s += __shfl_xor(s, 1, 64);
    s += __shfl_xor(s, 2, 64);
    if (l4 == 0) norms[quad] = sqrtf(s);
}

// cos + rowsums over USER rows only (each undirected edge once).
// User rowsum in-register; item rowsum via one scalar atomic per edge.
__global__ __launch_bounds__(256) void cos_row_k(const float* __restrict__ emb,
                                                 const float* __restrict__ norms,
                                                 const int* __restrict__ rp,
                                                 const int4* __restrict__ ent,
                                                 float* __restrict__ cosc,
                                                 float* __restrict__ rowsum, int NU) {
    int quad = (blockIdx.x * blockDim.x + threadIdx.x) >> 2;
    int l4   = threadIdx.x & 3;
    if (quad >= NU) return;
    int r  = quad;
    int p0 = rp[r], p1 = rp[r + 1];
    const float4* embv = (const float4*)emb;
    float4 A[4];
#pragma unroll
    for (int k = 0; k < 4; ++k) A[k] = embv[(size_t)r * 16 + k * 4 + l4];
    float nr = norms[r];
    float rs = 0.f;
    for (int p = p0; p < p1; ++p) {
        int d = ent[p].x;
        float dot = 0.f;
#pragma unroll
        for (int k = 0; k < 4; ++k) {
            float4 b = embv[(size_t)d * 16 + k * 4 + l4];
            dot += A[k].x * b.x + A[k].y * b.y + A[k].z * b.z + A[k].w * b.w;
        }
        dot += __shfl_xor(dot, 1, 64);
        dot += __shfl_xor(dot, 2, 64);
        float c = dot / fmaxf(nr * norms[d], 1e-8f);
        if (l4 == 0) {
            cosc[p] = c;
            atomicAdd(&rowsum[d], fabsf(c));
        }
        rs += fabsf(c);
    }
    if (l4 == 0) rowsum[r] = rs;
}

// Fused normalize + prune + memory EMA + SpMM for ALL rows. No atomics.
__global__ __launch_bounds__(256) void spmm_fused_k(const float* __restrict__ emb,
                                                    const int* __restrict__ rp,
                                                    const int4* __restrict__ ent,
                                                    const float* __restrict__ cosc,
                                                    const float* __restrict__ rowsum,
                                                    const float* __restrict__ Wp,
                                                    const float* __restrict__ bp,
                                                    float* __restrict__ memc, int useAdj,
                                                    float* __restrict__ out, int N) {
    int quad = (blockIdx.x * blockDim.x + threadIdx.x) >> 2;
    int l4   = threadIdx.x & 3;
    if (quad >= N) return;
    int r  = quad;
    int p0 = rp[r], p1 = rp[r + 1];
    float w0 = Wp[0], w1 = Wp[1], bb = bp[0];
    float rs  = rowsum[r];
    float rsg = rs > 0.f ? rs : 1.f;
    const float4* embv = (const float4*)emb;
    float4 acc[4];
#pragma unroll
    for (int k = 0; k < 4; ++k) acc[k] = make_float4(0.f, 0.f, 0.f, 0.f);
    for (int p = p0; p < p1; ++p) {
        int4 t = ent[p];
        int d = t.x;
        float a  = __int_as_float(t.y);
        float cv = cosc[t.z];
        float rd  = rowsum[d];
        float rdg = rd > 0.f ? rd : 1.f;
        float c  = cv / rsg;
        float cr = cv / rdg;
        float z  = w0 * c + w1 * cr + bb;
        float kept = (z > 0.f) ? c : 0.f;
        float mprev = useAdj ? a : memc[p];
        float m = 0.5f * mprev + 0.5f * kept;
        if (l4 == 0) memc[p] = m;
        float g = m * a;
#pragma unroll
        for (int k = 0; k < 4; ++k) {
            float4 b = embv[(size_t)d * 16 + k * 4 + l4];
            acc[k].x += g * b.x;
            acc[k].y += g * b.y;
            acc[k].z += g * b.z;
            acc[k].w += g * b.w;
        }
    }
    float4* outv = (float4*)out;
#pragma unroll
    for (int k = 0; k < 4; ++k) outv[(size_t)r * 16 + k * 4 + l4] = acc[k];
}

// Final layer: SpMM only for the selected 4096 rows; mem3 computed on the fly
// (not stored); result accumulated straight into acc.
__global__ __launch_bounds__(256) void sel_spmm_k(const float* __restrict__ emb,
                                                  const int* __restrict__ rp,
                                                  const int4* __restrict__ ent,
                                                  const float* __restrict__ cosc,
                                                  const float* __restrict__ rowsum,
                                                  const float* __restrict__ Wp,
                                                  const float* __restrict__ bp,
                                                  const float* __restrict__ memc,
                                                  const int* __restrict__ users,
                                                  const int* __restrict__ items,
                                                  float* __restrict__ acc,
                                                  int BU, int BI, int NU) {
    int quad = (blockIdx.x * blockDim.x + threadIdx.x) >> 2;
    int l4   = threadIdx.x & 3;
    if (quad >= BU + BI) return;
    int r  = (quad < BU) ? users[quad] : (NU + items[quad - BU]);
    int p0 = rp[r], p1 = rp[r + 1];
    float w0 = Wp[0], w1 = Wp[1], bb = bp[0];
    float rs  = rowsum[r];
    float rsg = rs > 0.f ? rs : 1.f;
    const float4* embv = (const float4*)emb;
    float4 a4[4];
#pragma unroll
    for (int k = 0; k < 4; ++k) a4[k] = make_float4(0.f, 0.f, 0.f, 0.f);
    for (int p = p0; p < p1; ++p) {
        int4 t = ent[p];
        int d = t.x;
        float a  = __int_as_float(t.y);
        float cv = cosc[t.z];
        float rd  = rowsum[d];
        float rdg = rd > 0.f ? rd : 1.f;
        float c  = cv / rsg;
        float cr = cv / rdg;
        float z  = w0 * c + w1 * cr + bb;
        float kept = (z > 0.f) ? c : 0.f;
        float m = 0.5f * memc[p] + 0.5f * kept;
        float g = m * a;
#pragma unroll
        for (int k = 0; k < 4; ++k) {
            float4 b = embv[(size_t)d * 16 + k * 4 + l4];
            a4[k].x += g * b.x;
            a4[k].y += g * b.y;
            a4[k].z += g * b.z;
            a4[k].w += g * b.w;
        }
    }
    float4* accv = (float4*)acc;
#pragma unroll
    for (int k = 0; k < 4; ++k) {
        float4 old = accv[(size_t)quad * 16 + k * 4 + l4];
        old.x += a4[k].x; old.y += a4[k].y; old.z += a4[k].z; old.w += a4[k].w;
        accv[(size_t)quad * 16 + k * 4 + l4] = old;
    }
}

// ================= selected-row accumulation + scoring =================

__global__ __launch_bounds__(256) void acc_update_k(const float* __restrict__ emb,
                                                    const int* __restrict__ users,
                                                    const int* __restrict__ items,
                                                    float* __restrict__ acc,
                                                    int BU, int BI, int NU, int init) {
    int tid = blockIdx.x * blockDim.x + threadIdx.x;
    int total = (BU + BI) * DD;
    if (tid >= total) return;
    int row = tid >> 6, d = tid & 63;
    int node = (row < BU) ? users[row] : (NU + items[row - BU]);
    float v = emb[(size_t)node * DD + d];
    if (init) acc[tid] = v;
    else      acc[tid] += v;
}

__global__ __launch_bounds__(256) void final_gemm_k(const float* __restrict__ acc,
                                                    float* __restrict__ out,
                                                    int BU, int BI) {
    __shared__ float Us[16][64];
    __shared__ float Is[16][65];
    int tx = threadIdx.x & 15, ty = threadIdx.x >> 4;
    int i0 = blockIdx.y * 16, j0 = blockIdx.x * 16;
    for (int t = threadIdx.x; t < 16 * 64; t += 256) {
        int r = t >> 6, k = t & 63;
        Us[r][k] = acc[(size_t)(i0 + r) * DD + k];
        Is[r][k] = acc[(size_t)(BU + j0 + r) * DD + k];
    }
    __syncthreads();
    float sum = 0.f;
#pragma unroll
    for (int k = 0; k < 64; ++k) sum += Us[ty][k] * Is[tx][k];
    float z = sum * 0.0625f;
    out[(size_t)(i0 + ty) * BI + (j0 + tx)] = 1.f / (1.f + expf(-z));
}

// ================= launch =================

extern "C" void kernel_launch(void* const* d_in, const int* in_sizes, int n_in,
                              void* d_out, int out_size, void* d_ws, size_t ws_size,
                              hipStream_t stream) {
    const int*   users    = (const int*)d_in[0];
    const int*   items    = (const int*)d_in[1];
    const float* user_emb = (const float*)d_in[2];
    const float* item_emb = (const float*)d_in[3];
    const float* Wp       = (const float*)d_in[4];
    const float* bp       = (const float*)d_in[5];
    const int*   src      = (const int*)d_in[6];
    const int*   dst      = (const int*)d_in[7];
    const float* adj      = (const float*)d_in[9];

    int BU = in_sizes[0];
    int BI = in_sizes[1];
    int NU = in_sizes[2] / DD;
    int NI = in_sizes[3] / DD;
    int Nn = NU + NI;
    int E  = in_sizes[6];
    int EH = E / 2;
    int M  = Nn + 1;
    int Mp = (M + 3) & ~3;

    // ---- workspace layout (ent first for 16B alignment) ----
    int*   ent_i  = (int*)d_ws;                        // E*4
    float* embA   = (float*)(ent_i + (size_t)E * 4);   // Nn*64
    float* embB   = embA + (size_t)Nn * DD;            // Nn*64
    float* norms  = embB + (size_t)Nn * DD;            // Nn
    float* rowsum = norms + Nn;                        // Nn
    float* cosc   = rowsum + Nn;                       // EH
    float* memc   = cosc + EH;                         // E
    float* acc    = memc + E;                          // (BU+BI)*64
    int*   deg    = (int*)(acc + (size_t)(BU + BI) * DD);  // Mp
    int*   rp     = deg + Mp;                          // Mp
    int*   rank   = rp + Mp;                           // E
    int*   partial= rank + E;                          // 256
    int4*  ent    = (int4*)ent_i;

    int eb  = (E + 255) / 256;
    int ehb = (EH + 255) / 256;
    int nc  = (M + 1023) / 1024;

    // ---- CSR build (atomic-free scatter via hist rank) ----
    hipMemsetAsync(deg, 0, sizeof(int) * (size_t)M, stream);
    hist_k<<<eb, 256, 0, stream>>>(src, deg, rank, E);
    scan1_k<<<nc, 256, 0, stream>>>(deg, rp, partial, M);
    scan2_k<<<1, 256, 0, stream>>>(partial, nc);
    scan3_k<<<(M + 255) / 256, 256, 0, stream>>>(rp, partial, M);
    scatter_k<<<ehb, 256, 0, stream>>>(src, dst, adj, rp, rank, ent, EH);

    // ---- emb0 = concat(user_emb, item_emb) ----
    hipMemcpyAsync(embA, user_emb, sizeof(float) * (size_t)NU * DD,
                   hipMemcpyDeviceToDevice, stream);
    hipMemcpyAsync(embA + (size_t)NU * DD, item_emb, sizeof(float) * (size_t)NI * DD,
                   hipMemcpyDeviceToDevice, stream);

    int accThreads = (BU + BI) * DD;
    acc_update_k<<<(accThreads + 255) / 256, 256, 0, stream>>>(embA, users, items, acc,
                                                               BU, BI, NU, 1);

    int rowBlocksU = (4 * NU + 255) / 256;
    int rowBlocksN = (4 * Nn + 255) / 256;
    int selBlocks  = (4 * (BU + BI) + 255) / 256;
    float* cur = embA;
    float* nxt = embB;
    for (int layer = 0; layer < 3; ++layer) {
        hipMemsetAsync(rowsum, 0, sizeof(float) * (size_t)Nn, stream);
        node_norms_k<<<rowBlocksN, 256, 0, stream>>>(cur, norms, Nn);
        cos_row_k<<<rowBlocksU, 256, 0, stream>>>(cur, norms, rp, ent, cosc, rowsum, NU);
        if (layer < 2) {
            spmm_fused_k<<<rowBlocksN, 256, 0, stream>>>(cur, rp, ent, cosc, rowsum,
                                                         Wp, bp, memc, layer == 0 ? 1 : 0,
                                                         nxt, Nn);
            acc_update_k<<<(accThreads + 255) / 256, 256, 0, stream>>>(nxt, users, items,
                                                                       acc, BU, BI, NU, 0);
            float* t = cur; cur = nxt; nxt = t;
        } else {
            sel_spmm_k<<<selBlocks, 256, 0, stream>>>(cur, rp, ent, cosc, rowsum,
                                                      Wp, bp, memc, users, items,
                                                      acc, BU, BI, NU);
        }
    }

    dim3 grid(BI / 16, BU / 16);
    final_gemm_k<<<grid, 256, 0, stream>>>(acc, (float*)d_out, BU, BI);
}

// Round 6
// 398.360 us; speedup vs baseline: 1.4802x; 1.1665x over previous
//
#include <hip/hip_runtime.h>
#include <math.h>

// LGNGuard: 3-layer guarded LightGCN propagation + sigmoid(U @ I^T) scoring.
// CSR by src (atomic-free scatter via hist-rank); cos once per undirected edge;
// prune+EMA fused into SpMM; layer-3 SpMM only for selected rows.
// Propagation table stored BF16 (halves random-gather bytes); all math f32.
// Quad layout: 4 lanes/row, 16 contiguous dims per lane.

#define DD 64
typedef unsigned int u32;

__device__ __forceinline__ float bflo(u32 u) { return __uint_as_float(u << 16); }
__device__ __forceinline__ float bfhi(u32 u) { return __uint_as_float(u & 0xFFFF0000u); }
__device__ __forceinline__ u32 bfpk(float lo, float hi) {   // RNE pack
    u32 a = __float_as_uint(lo), b = __float_as_uint(hi);
    a = (a + 0x7FFFu + ((a >> 16) & 1u)) >> 16;
    b = (b + 0x7FFFu + ((b >> 16) & 1u)) & 0xFFFF0000u;
    return a | b;
}
__device__ __forceinline__ void unp16(uint4 q0, uint4 q1, float* f) {
    f[0]=bflo(q0.x); f[1]=bfhi(q0.x); f[2]=bflo(q0.y); f[3]=bfhi(q0.y);
    f[4]=bflo(q0.z); f[5]=bfhi(q0.z); f[6]=bflo(q0.w); f[7]=bfhi(q0.w);
    f[8]=bflo(q1.x); f[9]=bfhi(q1.x); f[10]=bflo(q1.y); f[11]=bfhi(q1.y);
    f[12]=bflo(q1.z); f[13]=bfhi(q1.z); f[14]=bflo(q1.w); f[15]=bfhi(q1.w);
}

// ================= CSR build =================

__global__ __launch_bounds__(256) void hist_k(const int* __restrict__ src,
                                              int* __restrict__ deg,
                                              int* __restrict__ rank, int E) {
    int e = blockIdx.x * blockDim.x + threadIdx.x;
    if (e < E) rank[e] = atomicAdd(&deg[src[e]], 1);
}

__global__ __launch_bounds__(256) void scan1_k(const int* __restrict__ in,
                                               int* __restrict__ out,
                                               int* __restrict__ partial, int M) {
    __shared__ int sh[256];
    int base = blockIdx.x * 1024;
    int t = threadIdx.x;
    int i0 = base + t * 4;
    int v0 = (i0 + 0 < M) ? in[i0 + 0] : 0;
    int v1 = (i0 + 1 < M) ? in[i0 + 1] : 0;
    int v2 = (i0 + 2 < M) ? in[i0 + 2] : 0;
    int v3 = (i0 + 3 < M) ? in[i0 + 3] : 0;
    int tsum = v0 + v1 + v2 + v3;
    sh[t] = tsum;
    __syncthreads();
    for (int off = 1; off < 256; off <<= 1) {
        int x = (t >= off) ? sh[t - off] : 0;
        __syncthreads();
        sh[t] += x;
        __syncthreads();
    }
    int texcl = sh[t] - tsum;
    if (i0 + 0 < M) out[i0 + 0] = texcl;
    if (i0 + 1 < M) out[i0 + 1] = texcl + v0;
    if (i0 + 2 < M) out[i0 + 2] = texcl + v0 + v1;
    if (i0 + 3 < M) out[i0 + 3] = texcl + v0 + v1 + v2;
    if (t == 255) partial[blockIdx.x] = sh[255];
}

__global__ __launch_bounds__(256) void scan2_k(int* __restrict__ partial, int nc) {
    __shared__ int sh[256];
    int t = threadIdx.x;
    int v = (t < nc) ? partial[t] : 0;
    sh[t] = v;
    __syncthreads();
    for (int off = 1; off < 256; off <<= 1) {
        int x = (t >= off) ? sh[t - off] : 0;
        __syncthreads();
        sh[t] += x;
        __syncthreads();
    }
    if (t < nc) partial[t] = sh[t] - v;
}

__global__ __launch_bounds__(256) void scan3_k(int* __restrict__ out,
                                               const int* __restrict__ partial, int M) {
    int i = blockIdx.x * blockDim.x + threadIdx.x;
    if (i < M) out[i] += partial[i >> 10];
}

// one thread per UNDIRECTED edge; no atomics
__global__ __launch_bounds__(256) void scatter_k(const int* __restrict__ src,
                                                 const int* __restrict__ dst,
                                                 const float* __restrict__ adj,
                                                 const int* __restrict__ rp,
                                                 const int* __restrict__ rank,
                                                 int4* __restrict__ ent, int EH) {
    int e = blockIdx.x * blockDim.x + threadIdx.x;
    if (e >= EH) return;
    int u = src[e], i = dst[e];
    int ab = __float_as_int(adj[e]);
    int posU = rp[u] + rank[e];
    int posI = rp[i] + rank[e + EH];
    ent[posU] = make_int4(i, ab, posU, 0);
    ent[posI] = make_int4(u, ab, posU, 0);
}

// ================= bf16 table =================

// emb0 -> bf16 table
__global__ __launch_bounds__(256) void cvt_k(const float* __restrict__ ue,
                                             const float* __restrict__ ie,
                                             u32* __restrict__ tab, int NU, int Nn) {
    int idx = blockIdx.x * blockDim.x + threadIdx.x;
    if (idx >= Nn * 32) return;
    int node = idx >> 5, po = idx & 31;
    const float2* srow = (node < NU) ? (const float2*)(ue + (size_t)node * DD)
                                     : (const float2*)(ie + (size_t)(node - NU) * DD);
    float2 f = srow[po];
    tab[idx] = bfpk(f.x, f.y);
}

// ================= per-layer =================

__global__ __launch_bounds__(256) void node_norms_k(const u32* __restrict__ tab,
                                                    float* __restrict__ norms, int n) {
    int quad = (blockIdx.x * blockDim.x + threadIdx.x) >> 2;
    int l4   = threadIdx.x & 3;
    if (quad >= n) return;
    const uint4* p = (const uint4*)(tab + (size_t)quad * 32 + l4 * 8);
    float f[16];
    unp16(p[0], p[1], f);
    float s = 0.f;
#pragma unroll
    for (int i = 0; i < 16; ++i) s += f[i] * f[i];
    s += __shfl_xor(s, 1, 64);
    s += __shfl_xor(s, 2, 64);
    if (l4 == 0) norms[quad] = sqrtf(s);
}

// cos + rowsums over USER rows (each undirected edge once)
__global__ __launch_bounds__(256) void cos_row_k(const u32* __restrict__ tab,
                                                 const float* __restrict__ norms,
                                                 const int* __restrict__ rp,
                                                 const int4* __restrict__ ent,
                                                 float* __restrict__ cosc,
                                                 float* __restrict__ rowsum, int NU) {
    int quad = (blockIdx.x * blockDim.x + threadIdx.x) >> 2;
    int l4   = threadIdx.x & 3;
    if (quad >= NU) return;
    int r  = quad;
    int p0 = rp[r], p1 = rp[r + 1];
    const uint4* ap = (const uint4*)(tab + (size_t)r * 32 + l4 * 8);
    float A[16];
    unp16(ap[0], ap[1], A);
    float nr = norms[r];
    float rs = 0.f;
    for (int p = p0; p < p1; ++p) {
        int d = ent[p].x;
        const uint4* bp_ = (const uint4*)(tab + (size_t)d * 32 + l4 * 8);
        float B[16];
        unp16(bp_[0], bp_[1], B);
        float dot = 0.f;
#pragma unroll
        for (int i = 0; i < 16; ++i) dot += A[i] * B[i];
        dot += __shfl_xor(dot, 1, 64);
        dot += __shfl_xor(dot, 2, 64);
        float c = dot / fmaxf(nr * norms[d], 1e-8f);
        if (l4 == 0) {
            cosc[p] = c;
            atomicAdd(&rowsum[d], fabsf(c));
        }
        rs += fabsf(c);
    }
    if (l4 == 0) rowsum[r] = rs;
}

// fused normalize + prune + EMA + SpMM, all rows; bf16 in/out, f32 accumulate
__global__ __launch_bounds__(256) void spmm_fused_k(const u32* __restrict__ tab,
                                                    const int* __restrict__ rp,
                                                    const int4* __restrict__ ent,
                                                    const float* __restrict__ cosc,
                                                    const float* __restrict__ rowsum,
                                                    const float* __restrict__ Wp,
                                                    const float* __restrict__ bp,
                                                    float* __restrict__ memc, int useAdj,
                                                    u32* __restrict__ outtab, int N) {
    int quad = (blockIdx.x * blockDim.x + threadIdx.x) >> 2;
    int l4   = threadIdx.x & 3;
    if (quad >= N) return;
    int r  = quad;
    int p0 = rp[r], p1 = rp[r + 1];
    float w0 = Wp[0], w1 = Wp[1], bb = bp[0];
    float rs  = rowsum[r];
    float rsg = rs > 0.f ? rs : 1.f;
    float a16[16];
#pragma unroll
    for (int i = 0; i < 16; ++i) a16[i] = 0.f;
    for (int p = p0; p < p1; ++p) {
        int4 t = ent[p];
        int d = t.x;
        float a  = __int_as_float(t.y);
        float cv = cosc[t.z];
        float rd  = rowsum[d];
        float rdg = rd > 0.f ? rd : 1.f;
        float c  = cv / rsg;
        float cr = cv / rdg;
        float z  = w0 * c + w1 * cr + bb;
        float kept = (z > 0.f) ? c : 0.f;
        float mprev = useAdj ? a : memc[p];
        float m = 0.5f * mprev + 0.5f * kept;
        if (l4 == 0) memc[p] = m;
        float g = m * a;
        const uint4* bp_ = (const uint4*)(tab + (size_t)d * 32 + l4 * 8);
        float B[16];
        unp16(bp_[0], bp_[1], B);
#pragma unroll
        for (int i = 0; i < 16; ++i) a16[i] += g * B[i];
    }
    uint4 o0, o1;
    o0.x = bfpk(a16[0], a16[1]);  o0.y = bfpk(a16[2], a16[3]);
    o0.z = bfpk(a16[4], a16[5]);  o0.w = bfpk(a16[6], a16[7]);
    o1.x = bfpk(a16[8], a16[9]);  o1.y = bfpk(a16[10], a16[11]);
    o1.z = bfpk(a16[12], a16[13]); o1.w = bfpk(a16[14], a16[15]);
    uint4* op = (uint4*)(outtab + (size_t)r * 32 + l4 * 8);
    op[0] = o0;
    op[1] = o1;
}

// final layer: SpMM only for selected rows, accumulate f32 into acc
__global__ __launch_bounds__(256) void sel_spmm_k(const u32* __restrict__ tab,
                                                  const int* __restrict__ rp,
                                                  const int4* __restrict__ ent,
                                                  const float* __restrict__ cosc,
                                                  const float* __restrict__ rowsum,
                                                  const float* __restrict__ Wp,
                                                  const float* __restrict__ bp,
                                                  const float* __restrict__ memc,
                                                  const int* __restrict__ users,
                                                  const int* __restrict__ items,
                                                  float* __restrict__ acc,
                                                  int BU, int BI, int NU) {
    int quad = (blockIdx.x * blockDim.x + threadIdx.x) >> 2;
    int l4   = threadIdx.x & 3;
    if (quad >= BU + BI) return;
    int r  = (quad < BU) ? users[quad] : (NU + items[quad - BU]);
    int p0 = rp[r], p1 = rp[r + 1];
    float w0 = Wp[0], w1 = Wp[1], bb = bp[0];
    float rs  = rowsum[r];
    float rsg = rs > 0.f ? rs : 1.f;
    float a16[16];
#pragma unroll
    for (int i = 0; i < 16; ++i) a16[i] = 0.f;
    for (int p = p0; p < p1; ++p) {
        int4 t = ent[p];
        int d = t.x;
        float a  = __int_as_float(t.y);
        float cv = cosc[t.z];
        float rd  = rowsum[d];
        float rdg = rd > 0.f ? rd : 1.f;
        float c  = cv / rsg;
        float cr = cv / rdg;
        float z  = w0 * c + w1 * cr + bb;
        float kept = (z > 0.f) ? c : 0.f;
        float m = 0.5f * memc[p] + 0.5f * kept;
        float g = m * a;
        const uint4* bp_ = (const uint4*)(tab + (size_t)d * 32 + l4 * 8);
        float B[16];
        unp16(bp_[0], bp_[1], B);
#pragma unroll
        for (int i = 0; i < 16; ++i) a16[i] += g * B[i];
    }
    float4* av = (float4*)acc;
#pragma unroll
    for (int k = 0; k < 4; ++k) {
        float4 o = av[(size_t)quad * 16 + l4 * 4 + k];
        o.x += a16[k * 4 + 0]; o.y += a16[k * 4 + 1];
        o.z += a16[k * 4 + 2]; o.w += a16[k * 4 + 3];
        av[(size_t)quad * 16 + l4 * 4 + k] = o;
    }
}

// ================= selected-row accumulation + scoring =================

// init acc from f32 inputs (full precision for the dominant emb0 term)
__global__ __launch_bounds__(256) void acc_init_k(const float* __restrict__ ue,
                                                  const float* __restrict__ ie,
                                                  const int* __restrict__ users,
                                                  const int* __restrict__ items,
                                                  float* __restrict__ acc,
                                                  int BU, int BI, int NU) {
    int quad = (blockIdx.x * blockDim.x + threadIdx.x) >> 2;
    int l4   = threadIdx.x & 3;
    if (quad >= BU + BI) return;
    int node = (quad < BU) ? users[quad] : (NU + items[quad - BU]);
    const float4* srow = (node < NU) ? (const float4*)(ue + (size_t)node * DD)
                                     : (const float4*)(ie + (size_t)(node - NU) * DD);
    float4* av = (float4*)acc;
#pragma unroll
    for (int k = 0; k < 4; ++k)
        av[(size_t)quad * 16 + l4 * 4 + k] = srow[l4 * 4 + k];
}

// add a bf16-table row into acc
__global__ __launch_bounds__(256) void acc_upd_k(const u32* __restrict__ tab,
                                                 const int* __restrict__ users,
                                                 const int* __restrict__ items,
                                                 float* __restrict__ acc,
                                                 int BU, int BI, int NU) {
    int quad = (blockIdx.x * blockDim.x + threadIdx.x) >> 2;
    int l4   = threadIdx.x & 3;
    if (quad >= BU + BI) return;
    int node = (quad < BU) ? users[quad] : (NU + items[quad - BU]);
    const uint4* p = (const uint4*)(tab + (size_t)node * 32 + l4 * 8);
    float f[16];
    unp16(p[0], p[1], f);
    float4* av = (float4*)acc;
#pragma unroll
    for (int k = 0; k < 4; ++k) {
        float4 o = av[(size_t)quad * 16 + l4 * 4 + k];
        o.x += f[k * 4 + 0]; o.y += f[k * 4 + 1];
        o.z += f[k * 4 + 2]; o.w += f[k * 4 + 3];
        av[(size_t)quad * 16 + l4 * 4 + k] = o;
    }
}

// 64x64 tile, 4x4 outputs/thread, stride-65 LDS (2-way conflicts only)
__global__ __launch_bounds__(256) void final_gemm_k(const float* __restrict__ acc,
                                                    float* __restrict__ out,
                                                    int BU, int BI) {
    __shared__ float Us[64][65];
    __shared__ float Is[64][65];
    int t = threadIdx.x;
    int i0 = blockIdx.y * 64, j0 = blockIdx.x * 64;
#pragma unroll
    for (int i = 0; i < 4; ++i) {
        int f4 = t + i * 256;
        int r = f4 >> 4, c4 = (f4 & 15) * 4;
        float4 u4 = *(const float4*)&acc[(size_t)(i0 + r) * DD + c4];
        float4 v4 = *(const float4*)&acc[(size_t)(BU + j0 + r) * DD + c4];
        Us[r][c4 + 0] = u4.x; Us[r][c4 + 1] = u4.y;
        Us[r][c4 + 2] = u4.z; Us[r][c4 + 3] = u4.w;
        Is[r][c4 + 0] = v4.x; Is[r][c4 + 1] = v4.y;
        Is[r][c4 + 2] = v4.z; Is[r][c4 + 3] = v4.w;
    }
    __syncthreads();
    int tx = t & 15, ty = t >> 4;
    float s[4][4];
#pragma unroll
    for (int i = 0; i < 4; ++i)
#pragma unroll
        for (int j = 0; j < 4; ++j) s[i][j] = 0.f;
    for (int k = 0; k < 64; ++k) {
        float u[4], v[4];
#pragma unroll
        for (int i = 0; i < 4; ++i) u[i] = Us[ty * 4 + i][k];
#pragma unroll
        for (int j = 0; j < 4; ++j) v[j] = Is[tx * 4 + j][k];
#pragma unroll
        for (int i = 0; i < 4; ++i)
#pragma unroll
            for (int j = 0; j < 4; ++j) s[i][j] += u[i] * v[j];
    }
#pragma unroll
    for (int i = 0; i < 4; ++i) {
        float4 o;
        o.x = 1.f / (1.f + expf(-s[i][0] * 0.0625f));
        o.y = 1.f / (1.f + expf(-s[i][1] * 0.0625f));
        o.z = 1.f / (1.f + expf(-s[i][2] * 0.0625f));
        o.w = 1.f / (1.f + expf(-s[i][3] * 0.0625f));
        *(float4*)&out[(size_t)(i0 + ty * 4 + i) * BI + j0 + tx * 4] = o;
    }
}

// ================= launch =================

extern "C" void kernel_launch(void* const* d_in, const int* in_sizes, int n_in,
                              void* d_out, int out_size, void* d_ws, size_t ws_size,
                              hipStream_t stream) {
    const int*   users    = (const int*)d_in[0];
    const int*   items    = (const int*)d_in[1];
    const float* user_emb = (const float*)d_in[2];
    const float* item_emb = (const float*)d_in[3];
    const float* Wp       = (const float*)d_in[4];
    const float* bp       = (const float*)d_in[5];
    const int*   src      = (const int*)d_in[6];
    const int*   dst      = (const int*)d_in[7];
    const float* adj      = (const float*)d_in[9];

    int BU = in_sizes[0];
    int BI = in_sizes[1];
    int NU = in_sizes[2] / DD;
    int NI = in_sizes[3] / DD;
    int Nn = NU + NI;
    int E  = in_sizes[6];
    int EH = E / 2;
    int M  = Nn + 1;
    int Mp = (M + 3) & ~3;

    // ---- workspace (16B-aligned blocks first) ----
    int4*  ent    = (int4*)d_ws;                             // E
    u32*   tabA   = (u32*)(ent + E);                         // Nn*32
    u32*   tabB   = tabA + (size_t)Nn * 32;                  // Nn*32
    float* norms  = (float*)(tabB + (size_t)Nn * 32);        // Nn
    float* rowsum = norms + Nn;                              // Nn
    float* cosc   = rowsum + Nn;                             // EH
    float* memc   = cosc + EH;                               // E
    float* acc    = memc + E;                                // (BU+BI)*64
    int*   deg    = (int*)(acc + (size_t)(BU + BI) * DD);    // Mp
    int*   rp     = deg + Mp;                                // Mp
    int*   rank   = rp + Mp;                                 // E
    int*   partial= rank + E;                                // 256

    int eb  = (E + 255) / 256;
    int ehb = (EH + 255) / 256;
    int nc  = (M + 1023) / 1024;

    // ---- CSR build ----
    hipMemsetAsync(deg, 0, sizeof(int) * (size_t)M, stream);
    hist_k<<<eb, 256, 0, stream>>>(src, deg, rank, E);
    scan1_k<<<nc, 256, 0, stream>>>(deg, rp, partial, M);
    scan2_k<<<1, 256, 0, stream>>>(partial, nc);
    scan3_k<<<(M + 255) / 256, 256, 0, stream>>>(rp, partial, M);
    scatter_k<<<ehb, 256, 0, stream>>>(src, dst, adj, rp, rank, ent, EH);

    // ---- bf16 table + acc init ----
    cvt_k<<<(Nn * 32 + 255) / 256, 256, 0, stream>>>(user_emb, item_emb, tabA, NU, Nn);
    int selBlocks = (4 * (BU + BI) + 255) / 256;
    acc_init_k<<<selBlocks, 256, 0, stream>>>(user_emb, item_emb, users, items, acc,
                                              BU, BI, NU);

    int rowBlocksU = (4 * NU + 255) / 256;
    int rowBlocksN = (4 * Nn + 255) / 256;
    u32* cur = tabA;
    u32* nxt = tabB;
    for (int layer = 0; layer < 3; ++layer) {
        hipMemsetAsync(rowsum + NU, 0, sizeof(float) * (size_t)NI, stream);
        node_norms_k<<<rowBlocksN, 256, 0, stream>>>(cur, norms, Nn);
        cos_row_k<<<rowBlocksU, 256, 0, stream>>>(cur, norms, rp, ent, cosc, rowsum, NU);
        if (layer < 2) {
            spmm_fused_k<<<rowBlocksN, 256, 0, stream>>>(cur, rp, ent, cosc, rowsum,
                                                         Wp, bp, memc, layer == 0 ? 1 : 0,
                                                         nxt, Nn);
            acc_upd_k<<<selBlocks, 256, 0, stream>>>(nxt, users, items, acc, BU, BI, NU);
            u32* t = cur; cur = nxt; nxt = t;
        } else {
            sel_spmm_k<<<selBlocks, 256, 0, stream>>>(cur, rp, ent, cosc, rowsum,
                                                      Wp, bp, memc, users, items,
                                                      acc, BU, BI, NU);
        }
    }

    dim3 grid(BI / 64, BU / 64);
    final_gemm_k<<<grid, 256, 0, stream>>>(acc, (float*)d_out, BU, BI);
}

// Round 7
// 358.675 us; speedup vs baseline: 1.6439x; 1.1106x over previous
//
#include <hip/hip_runtime.h>
#include <math.h>

// LGNGuard: 3-layer guarded LightGCN propagation + sigmoid(U @ I^T) scoring.
// CSR by src (atomic-free scatter); cos once per undirected edge; prune+EMA
// fused into SpMM; layer-3 SpMM only for selected rows. BF16 table, f32 math.
// Edge loops unrolled x4 for memory-level parallelism (latency-bound gathers).
// ent = int2{dst,adj}; user-side cos index == p (rp[NU]==EH); item side: cidx.

#define DD 64
typedef unsigned int u32;

__device__ __forceinline__ float bflo(u32 u) { return __uint_as_float(u << 16); }
__device__ __forceinline__ float bfhi(u32 u) { return __uint_as_float(u & 0xFFFF0000u); }
__device__ __forceinline__ u32 bfpk(float lo, float hi) {   // RNE pack
    u32 a = __float_as_uint(lo), b = __float_as_uint(hi);
    a = (a + 0x7FFFu + ((a >> 16) & 1u)) >> 16;
    b = (b + 0x7FFFu + ((b >> 16) & 1u)) & 0xFFFF0000u;
    return a | b;
}
__device__ __forceinline__ void unp16(uint4 q0, uint4 q1, float* f) {
    f[0]=bflo(q0.x); f[1]=bfhi(q0.x); f[2]=bflo(q0.y); f[3]=bfhi(q0.y);
    f[4]=bflo(q0.z); f[5]=bfhi(q0.z); f[6]=bflo(q0.w); f[7]=bfhi(q0.w);
    f[8]=bflo(q1.x); f[9]=bfhi(q1.x); f[10]=bflo(q1.y); f[11]=bfhi(q1.y);
    f[12]=bflo(q1.z); f[13]=bfhi(q1.z); f[14]=bflo(q1.w); f[15]=bfhi(q1.w);
}

// ================= CSR build =================

__global__ __launch_bounds__(256) void hist_k(const int* __restrict__ src,
                                              int* __restrict__ deg,
                                              int* __restrict__ rank, int E) {
    int e = blockIdx.x * blockDim.x + threadIdx.x;
    if (e < E) rank[e] = atomicAdd(&deg[src[e]], 1);
}

__global__ __launch_bounds__(256) void scan1_k(const int* __restrict__ in,
                                               int* __restrict__ out,
                                               int* __restrict__ partial, int M) {
    __shared__ int sh[256];
    int base = blockIdx.x * 1024;
    int t = threadIdx.x;
    int i0 = base + t * 4;
    int v0 = (i0 + 0 < M) ? in[i0 + 0] : 0;
    int v1 = (i0 + 1 < M) ? in[i0 + 1] : 0;
    int v2 = (i0 + 2 < M) ? in[i0 + 2] : 0;
    int v3 = (i0 + 3 < M) ? in[i0 + 3] : 0;
    int tsum = v0 + v1 + v2 + v3;
    sh[t] = tsum;
    __syncthreads();
    for (int off = 1; off < 256; off <<= 1) {
        int x = (t >= off) ? sh[t - off] : 0;
        __syncthreads();
        sh[t] += x;
        __syncthreads();
    }
    int texcl = sh[t] - tsum;
    if (i0 + 0 < M) out[i0 + 0] = texcl;
    if (i0 + 1 < M) out[i0 + 1] = texcl + v0;
    if (i0 + 2 < M) out[i0 + 2] = texcl + v0 + v1;
    if (i0 + 3 < M) out[i0 + 3] = texcl + v0 + v1 + v2;
    if (t == 255) partial[blockIdx.x] = sh[255];
}

__global__ __launch_bounds__(256) void scan2_k(int* __restrict__ partial, int nc) {
    __shared__ int sh[256];
    int t = threadIdx.x;
    int v = (t < nc) ? partial[t] : 0;
    sh[t] = v;
    __syncthreads();
    for (int off = 1; off < 256; off <<= 1) {
        int x = (t >= off) ? sh[t - off] : 0;
        __syncthreads();
        sh[t] += x;
        __syncthreads();
    }
    if (t < nc) partial[t] = sh[t] - v;
}

__global__ __launch_bounds__(256) void scan3_k(int* __restrict__ out,
                                               const int* __restrict__ partial, int M) {
    int i = blockIdx.x * blockDim.x + threadIdx.x;
    if (i < M) out[i] += partial[i >> 10];
}

// one thread per UNDIRECTED edge; no atomics
__global__ __launch_bounds__(256) void scatter_k(const int* __restrict__ src,
                                                 const int* __restrict__ dst,
                                                 const float* __restrict__ adj,
                                                 const int* __restrict__ rp,
                                                 const int* __restrict__ rank,
                                                 int2* __restrict__ ent,
                                                 int* __restrict__ cidx, int EH) {
    int e = blockIdx.x * blockDim.x + threadIdx.x;
    if (e >= EH) return;
    int u = src[e], i = dst[e];
    int ab = __float_as_int(adj[e]);
    int posU = rp[u] + rank[e];
    int posI = rp[i] + rank[e + EH];
    ent[posU] = make_int2(i, ab);
    ent[posI] = make_int2(u, ab);
    cidx[posI - EH] = posU;
}

// ================= bf16 table =================

__global__ __launch_bounds__(256) void cvt_k(const float* __restrict__ ue,
                                             const float* __restrict__ ie,
                                             u32* __restrict__ tab, int NU, int Nn) {
    int idx = blockIdx.x * blockDim.x + threadIdx.x;
    if (idx >= Nn * 32) return;
    int node = idx >> 5, po = idx & 31;
    const float2* srow = (node < NU) ? (const float2*)(ue + (size_t)node * DD)
                                     : (const float2*)(ie + (size_t)(node - NU) * DD);
    float2 f = srow[po];
    tab[idx] = bfpk(f.x, f.y);
}

// ================= per-layer =================

__global__ __launch_bounds__(256) void node_norms_k(const u32* __restrict__ tab,
                                                    float* __restrict__ norms, int n) {
    int quad = (blockIdx.x * blockDim.x + threadIdx.x) >> 2;
    int l4   = threadIdx.x & 3;
    if (quad >= n) return;
    const uint4* p = (const uint4*)(tab + (size_t)quad * 32 + l4 * 8);
    float f[16];
    unp16(p[0], p[1], f);
    float s = 0.f;
#pragma unroll
    for (int i = 0; i < 16; ++i) s += f[i] * f[i];
    s += __shfl_xor(s, 1, 64);
    s += __shfl_xor(s, 2, 64);
    if (l4 == 0) norms[quad] = sqrtf(s);
}

// cos + rowsums over USER rows (each undirected edge once), unroll x4
__global__ __launch_bounds__(256) void cos_row_k(const u32* __restrict__ tab,
                                                 const float* __restrict__ norms,
                                                 const int* __restrict__ rp,
                                                 const int2* __restrict__ ent,
                                                 float* __restrict__ cosc,
                                                 float* __restrict__ rowsum, int NU) {
    int quad = (blockIdx.x * blockDim.x + threadIdx.x) >> 2;
    int l4   = threadIdx.x & 3;
    if (quad >= NU) return;
    int r  = quad;
    int p0 = rp[r], p1 = rp[r + 1];
    const uint4* ap = (const uint4*)(tab + (size_t)r * 32 + l4 * 8);
    float A[16];
    unp16(ap[0], ap[1], A);
    float nr = norms[r];
    float rs = 0.f;
    int p = p0;
    for (; p + 4 <= p1; p += 4) {
        int d0 = ent[p].x, d1 = ent[p+1].x, d2 = ent[p+2].x, d3 = ent[p+3].x;
        const uint4* q0 = (const uint4*)(tab + (size_t)d0 * 32 + l4 * 8);
        const uint4* q1 = (const uint4*)(tab + (size_t)d1 * 32 + l4 * 8);
        const uint4* q2 = (const uint4*)(tab + (size_t)d2 * 32 + l4 * 8);
        const uint4* q3 = (const uint4*)(tab + (size_t)d3 * 32 + l4 * 8);
        uint4 b00 = q0[0], b01 = q0[1];
        uint4 b10 = q1[0], b11 = q1[1];
        uint4 b20 = q2[0], b21 = q2[1];
        uint4 b30 = q3[0], b31 = q3[1];
        float n0 = norms[d0], n1 = norms[d1], n2 = norms[d2], n3 = norms[d3];
        float B[16];
        float dt0 = 0.f, dt1 = 0.f, dt2 = 0.f, dt3 = 0.f;
        unp16(b00, b01, B);
#pragma unroll
        for (int i = 0; i < 16; ++i) dt0 += A[i] * B[i];
        unp16(b10, b11, B);
#pragma unroll
        for (int i = 0; i < 16; ++i) dt1 += A[i] * B[i];
        unp16(b20, b21, B);
#pragma unroll
        for (int i = 0; i < 16; ++i) dt2 += A[i] * B[i];
        unp16(b30, b31, B);
#pragma unroll
        for (int i = 0; i < 16; ++i) dt3 += A[i] * B[i];
        dt0 += __shfl_xor(dt0, 1, 64); dt0 += __shfl_xor(dt0, 2, 64);
        dt1 += __shfl_xor(dt1, 1, 64); dt1 += __shfl_xor(dt1, 2, 64);
        dt2 += __shfl_xor(dt2, 1, 64); dt2 += __shfl_xor(dt2, 2, 64);
        dt3 += __shfl_xor(dt3, 1, 64); dt3 += __shfl_xor(dt3, 2, 64);
        float c0 = dt0 / fmaxf(nr * n0, 1e-8f);
        float c1 = dt1 / fmaxf(nr * n1, 1e-8f);
        float c2 = dt2 / fmaxf(nr * n2, 1e-8f);
        float c3 = dt3 / fmaxf(nr * n3, 1e-8f);
        if (l4 == 0) {
            cosc[p]   = c0; atomicAdd(&rowsum[d0], fabsf(c0));
            cosc[p+1] = c1; atomicAdd(&rowsum[d1], fabsf(c1));
            cosc[p+2] = c2; atomicAdd(&rowsum[d2], fabsf(c2));
            cosc[p+3] = c3; atomicAdd(&rowsum[d3], fabsf(c3));
        }
        rs += fabsf(c0) + fabsf(c1) + fabsf(c2) + fabsf(c3);
    }
    for (; p < p1; ++p) {
        int d = ent[p].x;
        const uint4* q = (const uint4*)(tab + (size_t)d * 32 + l4 * 8);
        uint4 b0 = q[0], b1 = q[1];
        float B[16];
        unp16(b0, b1, B);
        float dot = 0.f;
#pragma unroll
        for (int i = 0; i < 16; ++i) dot += A[i] * B[i];
        dot += __shfl_xor(dot, 1, 64);
        dot += __shfl_xor(dot, 2, 64);
        float c = dot / fmaxf(nr * norms[d], 1e-8f);
        if (l4 == 0) {
            cosc[p] = c;
            atomicAdd(&rowsum[d], fabsf(c));
        }
        rs += fabsf(c);
    }
    if (l4 == 0) rowsum[r] = rs;
}

// fused normalize + prune + EMA + SpMM, all rows, unroll x4
__global__ __launch_bounds__(256) void spmm_fused_k(const u32* __restrict__ tab,
                                                    const int* __restrict__ rp,
                                                    const int2* __restrict__ ent,
                                                    const int* __restrict__ cidx,
                                                    const float* __restrict__ cosc,
                                                    const float* __restrict__ rowsum,
                                                    const float* __restrict__ Wp,
                                                    const float* __restrict__ bp,
                                                    float* __restrict__ memc, int useAdj,
                                                    u32* __restrict__ outtab,
                                                    int NU, int EH, int N) {
    int quad = (blockIdx.x * blockDim.x + threadIdx.x) >> 2;
    int l4   = threadIdx.x & 3;
    if (quad >= N) return;
    int r  = quad;
    int p0 = rp[r], p1 = rp[r + 1];
    bool isU = (r < NU);
    float w0 = Wp[0], w1 = Wp[1], bb = bp[0];
    float rs  = rowsum[r];
    float rsg = rs > 0.f ? rs : 1.f;
    float a16[16];
#pragma unroll
    for (int i = 0; i < 16; ++i) a16[i] = 0.f;
    int p = p0;
    for (; p + 4 <= p1; p += 4) {
        int2 t0 = ent[p], t1 = ent[p+1], t2 = ent[p+2], t3 = ent[p+3];
        int c0i = isU ? p   : cidx[p   - EH];
        int c1i = isU ? p+1 : cidx[p+1 - EH];
        int c2i = isU ? p+2 : cidx[p+2 - EH];
        int c3i = isU ? p+3 : cidx[p+3 - EH];
        const uint4* q0 = (const uint4*)(tab + (size_t)t0.x * 32 + l4 * 8);
        const uint4* q1 = (const uint4*)(tab + (size_t)t1.x * 32 + l4 * 8);
        const uint4* q2 = (const uint4*)(tab + (size_t)t2.x * 32 + l4 * 8);
        const uint4* q3 = (const uint4*)(tab + (size_t)t3.x * 32 + l4 * 8);
        uint4 b00 = q0[0], b01 = q0[1];
        uint4 b10 = q1[0], b11 = q1[1];
        uint4 b20 = q2[0], b21 = q2[1];
        uint4 b30 = q3[0], b31 = q3[1];
        float cv0 = cosc[c0i], cv1 = cosc[c1i], cv2 = cosc[c2i], cv3 = cosc[c3i];
        float rd0 = rowsum[t0.x], rd1 = rowsum[t1.x];
        float rd2 = rowsum[t2.x], rd3 = rowsum[t3.x];
        float mp0 = useAdj ? __int_as_float(t0.y) : memc[p];
        float mp1 = useAdj ? __int_as_float(t1.y) : memc[p+1];
        float mp2 = useAdj ? __int_as_float(t2.y) : memc[p+2];
        float mp3 = useAdj ? __int_as_float(t3.y) : memc[p+3];
        float B[16];
#define EDGE(cv, rd, mp, ty, bA, bB, pp)                                    \
        {                                                                   \
            float a = __int_as_float(ty);                                   \
            float rdg = rd > 0.f ? rd : 1.f;                                \
            float c  = cv / rsg;                                            \
            float cr = cv / rdg;                                            \
            float z  = w0 * c + w1 * cr + bb;                               \
            float kept = (z > 0.f) ? c : 0.f;                               \
            float m = 0.5f * mp + 0.5f * kept;                              \
            if (l4 == 0) memc[pp] = m;                                      \
            float g = m * a;                                                \
            unp16(bA, bB, B);                                               \
            _Pragma("unroll")                                               \
            for (int i = 0; i < 16; ++i) a16[i] += g * B[i];                \
        }
        EDGE(cv0, rd0, mp0, t0.y, b00, b01, p)
        EDGE(cv1, rd1, mp1, t1.y, b10, b11, p+1)
        EDGE(cv2, rd2, mp2, t2.y, b20, b21, p+2)
        EDGE(cv3, rd3, mp3, t3.y, b30, b31, p+3)
    }
    for (; p < p1; ++p) {
        int2 t = ent[p];
        int ci = isU ? p : cidx[p - EH];
        const uint4* q = (const uint4*)(tab + (size_t)t.x * 32 + l4 * 8);
        uint4 b0 = q[0], b1 = q[1];
        float cv = cosc[ci];
        float rd = rowsum[t.x];
        float mp = useAdj ? __int_as_float(t.y) : memc[p];
        float B[16];
        EDGE(cv, rd, mp, t.y, b0, b1, p)
    }
#undef EDGE
    uint4 o0, o1;
    o0.x = bfpk(a16[0], a16[1]);   o0.y = bfpk(a16[2], a16[3]);
    o0.z = bfpk(a16[4], a16[5]);   o0.w = bfpk(a16[6], a16[7]);
    o1.x = bfpk(a16[8], a16[9]);   o1.y = bfpk(a16[10], a16[11]);
    o1.z = bfpk(a16[12], a16[13]); o1.w = bfpk(a16[14], a16[15]);
    uint4* op = (uint4*)(outtab + (size_t)r * 32 + l4 * 8);
    op[0] = o0;
    op[1] = o1;
}

// final layer: SpMM only for selected rows, accumulate f32 into acc, unroll x4
__global__ __launch_bounds__(256) void sel_spmm_k(const u32* __restrict__ tab,
                                                  const int* __restrict__ rp,
                                                  const int2* __restrict__ ent,
                                                  const int* __restrict__ cidx,
                                                  const float* __restrict__ cosc,
                                                  const float* __restrict__ rowsum,
                                                  const float* __restrict__ Wp,
                                                  const float* __restrict__ bp,
                                                  const float* __restrict__ memc,
                                                  const int* __restrict__ users,
                                                  const int* __restrict__ items,
                                                  float* __restrict__ acc,
                                                  int BU, int BI, int NU, int EH) {
    int quad = (blockIdx.x * blockDim.x + threadIdx.x) >> 2;
    int l4   = threadIdx.x & 3;
    if (quad >= BU + BI) return;
    int r  = (quad < BU) ? users[quad] : (NU + items[quad - BU]);
    int p0 = rp[r], p1 = rp[r + 1];
    bool isU = (r < NU);
    float w0 = Wp[0], w1 = Wp[1], bb = bp[0];
    float rs  = rowsum[r];
    float rsg = rs > 0.f ? rs : 1.f;
    float a16[16];
#pragma unroll
    for (int i = 0; i < 16; ++i) a16[i] = 0.f;
    int p = p0;
    for (; p + 4 <= p1; p += 4) {
        int2 t0 = ent[p], t1 = ent[p+1], t2 = ent[p+2], t3 = ent[p+3];
        int c0i = isU ? p   : cidx[p   - EH];
        int c1i = isU ? p+1 : cidx[p+1 - EH];
        int c2i = isU ? p+2 : cidx[p+2 - EH];
        int c3i = isU ? p+3 : cidx[p+3 - EH];
        const uint4* q0 = (const uint4*)(tab + (size_t)t0.x * 32 + l4 * 8);
        const uint4* q1 = (const uint4*)(tab + (size_t)t1.x * 32 + l4 * 8);
        const uint4* q2 = (const uint4*)(tab + (size_t)t2.x * 32 + l4 * 8);
        const uint4* q3 = (const uint4*)(tab + (size_t)t3.x * 32 + l4 * 8);
        uint4 b00 = q0[0], b01 = q0[1];
        uint4 b10 = q1[0], b11 = q1[1];
        uint4 b20 = q2[0], b21 = q2[1];
        uint4 b30 = q3[0], b31 = q3[1];
        float cv0 = cosc[c0i], cv1 = cosc[c1i], cv2 = cosc[c2i], cv3 = cosc[c3i];
        float rd0 = rowsum[t0.x], rd1 = rowsum[t1.x];
        float rd2 = rowsum[t2.x], rd3 = rowsum[t3.x];
        float mm0 = memc[p], mm1 = memc[p+1], mm2 = memc[p+2], mm3 = memc[p+3];
        float B[16];
#define EDGES(cv, rd, mm, ty, bA, bB)                                       \
        {                                                                   \
            float a = __int_as_float(ty);                                   \
            float rdg = rd > 0.f ? rd : 1.f;                                \
            float c  = cv / rsg;                                            \
            float cr = cv / rdg;                                            \
            float z  = w0 * c + w1 * cr + bb;                               \
            float kept = (z > 0.f) ? c : 0.f;                               \
            float m = 0.5f * mm + 0.5f * kept;                              \
            float g = m * a;                                                \
            unp16(bA, bB, B);                                               \
            _Pragma("unroll")                                               \
            for (int i = 0; i < 16; ++i) a16[i] += g * B[i];                \
        }
        EDGES(cv0, rd0, mm0, t0.y, b00, b01)
        EDGES(cv1, rd1, mm1, t1.y, b10, b11)
        EDGES(cv2, rd2, mm2, t2.y, b20, b21)
        EDGES(cv3, rd3, mm3, t3.y, b30, b31)
    }
    for (; p < p1; ++p) {
        int2 t = ent[p];
        int ci = isU ? p : cidx[p - EH];
        const uint4* q = (const uint4*)(tab + (size_t)t.x * 32 + l4 * 8);
        uint4 b0 = q[0], b1 = q[1];
        float cv = cosc[ci];
        float rd = rowsum[t.x];
        float mm = memc[p];
        float B[16];
        EDGES(cv, rd, mm, t.y, b0, b1)
    }
#undef EDGES
    float4* av = (float4*)acc;
#pragma unroll
    for (int k = 0; k < 4; ++k) {
        float4 o = av[(size_t)quad * 16 + l4 * 4 + k];
        o.x += a16[k * 4 + 0]; o.y += a16[k * 4 + 1];
        o.z += a16[k * 4 + 2]; o.w += a16[k * 4 + 3];
        av[(size_t)quad * 16 + l4 * 4 + k] = o;
    }
}

// ================= selected-row accumulation + scoring =================

__global__ __launch_bounds__(256) void acc_init_k(const float* __restrict__ ue,
                                                  const float* __restrict__ ie,
                                                  const int* __restrict__ users,
                                                  const int* __restrict__ items,
                                                  float* __restrict__ acc,
                                                  int BU, int BI, int NU) {
    int quad = (blockIdx.x * blockDim.x + threadIdx.x) >> 2;
    int l4   = threadIdx.x & 3;
    if (quad >= BU + BI) return;
    int node = (quad < BU) ? users[quad] : (NU + items[quad - BU]);
    const float4* srow = (node < NU) ? (const float4*)(ue + (size_t)node * DD)
                                     : (const float4*)(ie + (size_t)(node - NU) * DD);
    float4* av = (float4*)acc;
#pragma unroll
    for (int k = 0; k < 4; ++k)
        av[(size_t)quad * 16 + l4 * 4 + k] = srow[l4 * 4 + k];
}

__global__ __launch_bounds__(256) void acc_upd_k(const u32* __restrict__ tab,
                                                 const int* __restrict__ users,
                                                 const int* __restrict__ items,
                                                 float* __restrict__ acc,
                                                 int BU, int BI, int NU) {
    int quad = (blockIdx.x * blockDim.x + threadIdx.x) >> 2;
    int l4   = threadIdx.x & 3;
    if (quad >= BU + BI) return;
    int node = (quad < BU) ? users[quad] : (NU + items[quad - BU]);
    const uint4* p = (const uint4*)(tab + (size_t)node * 32 + l4 * 8);
    float f[16];
    unp16(p[0], p[1], f);
    float4* av = (float4*)acc;
#pragma unroll
    for (int k = 0; k < 4; ++k) {
        float4 o = av[(size_t)quad * 16 + l4 * 4 + k];
        o.x += f[k * 4 + 0]; o.y += f[k * 4 + 1];
        o.z += f[k * 4 + 2]; o.w += f[k * 4 + 3];
        av[(size_t)quad * 16 + l4 * 4 + k] = o;
    }
}

// 64x64 tile, 4x4 outputs/thread, stride-65 LDS
__global__ __launch_bounds__(256) void final_gemm_k(const float* __restrict__ acc,
                                                    float* __restrict__ out,
                                                    int BU, int BI) {
    __shared__ float Us[64][65];
    __shared__ float Is[64][65];
    int t = threadIdx.x;
    int i0 = blockIdx.y * 64, j0 = blockIdx.x * 64;
#pragma unroll
    for (int i = 0; i < 4; ++i) {
        int f4 = t + i * 256;
        int r = f4 >> 4, c4 = (f4 & 15) * 4;
        float4 u4 = *(const float4*)&acc[(size_t)(i0 + r) * DD + c4];
        float4 v4 = *(const float4*)&acc[(size_t)(BU + j0 + r) * DD + c4];
        Us[r][c4 + 0] = u4.x; Us[r][c4 + 1] = u4.y;
        Us[r][c4 + 2] = u4.z; Us[r][c4 + 3] = u4.w;
        Is[r][c4 + 0] = v4.x; Is[r][c4 + 1] = v4.y;
        Is[r][c4 + 2] = v4.z; Is[r][c4 + 3] = v4.w;
    }
    __syncthreads();
    int tx = t & 15, ty = t >> 4;
    float s[4][4];
#pragma unroll
    for (int i = 0; i < 4; ++i)
#pragma unroll
        for (int j = 0; j < 4; ++j) s[i][j] = 0.f;
    for (int k = 0; k < 64; ++k) {
        float u[4], v[4];
#pragma unroll
        for (int i = 0; i < 4; ++i) u[i] = Us[ty * 4 + i][k];
#pragma unroll
        for (int j = 0; j < 4; ++j) v[j] = Is[tx * 4 + j][k];
#pragma unroll
        for (int i = 0; i < 4; ++i)
#pragma unroll
            for (int j = 0; j < 4; ++j) s[i][j] += u[i] * v[j];
    }
#pragma unroll
    for (int i = 0; i < 4; ++i) {
        float4 o;
        o.x = 1.f / (1.f + expf(-s[i][0] * 0.0625f));
        o.y = 1.f / (1.f + expf(-s[i][1] * 0.0625f));
        o.z = 1.f / (1.f + expf(-s[i][2] * 0.0625f));
        o.w = 1.f / (1.f + expf(-s[i][3] * 0.0625f));
        *(float4*)&out[(size_t)(i0 + ty * 4 + i) * BI + j0 + tx * 4] = o;
    }
}

// ================= launch =================

extern "C" void kernel_launch(void* const* d_in, const int* in_sizes, int n_in,
                              void* d_out, int out_size, void* d_ws, size_t ws_size,
                              hipStream_t stream) {
    const int*   users    = (const int*)d_in[0];
    const int*   items    = (const int*)d_in[1];
    const float* user_emb = (const float*)d_in[2];
    const float* item_emb = (const float*)d_in[3];
    const float* Wp       = (const float*)d_in[4];
    const float* bp       = (const float*)d_in[5];
    const int*   src      = (const int*)d_in[6];
    const int*   dst      = (const int*)d_in[7];
    const float* adj      = (const float*)d_in[9];

    int BU = in_sizes[0];
    int BI = in_sizes[1];
    int NU = in_sizes[2] / DD;
    int NI = in_sizes[3] / DD;
    int Nn = NU + NI;
    int E  = in_sizes[6];
    int EH = E / 2;
    int M  = Nn + 1;
    int Mp = (M + 3) & ~3;

    // ---- workspace (16B-aligned blocks first) ----
    u32*   tabA   = (u32*)d_ws;                              // Nn*32
    u32*   tabB   = tabA + (size_t)Nn * 32;                  // Nn*32
    int2*  ent    = (int2*)(tabB + (size_t)Nn * 32);         // E
    int*   cidx   = (int*)(ent + E);                         // EH
    float* norms  = (float*)(cidx + EH);                     // Nn
    float* rowsum = norms + Nn;                              // Nn
    float* cosc   = rowsum + Nn;                             // EH
    float* memc   = cosc + EH;                               // E
    float* acc    = memc + E;                                // (BU+BI)*64
    int*   deg    = (int*)(acc + (size_t)(BU + BI) * DD);    // Mp
    int*   rp     = deg + Mp;                                // Mp
    int*   rank   = rp + Mp;                                 // E
    int*   partial= rank + E;                                // 256

    int eb  = (E + 255) / 256;
    int ehb = (EH + 255) / 256;
    int nc  = (M + 1023) / 1024;

    // ---- CSR build ----
    hipMemsetAsync(deg, 0, sizeof(int) * (size_t)M, stream);
    hist_k<<<eb, 256, 0, stream>>>(src, deg, rank, E);
    scan1_k<<<nc, 256, 0, stream>>>(deg, rp, partial, M);
    scan2_k<<<1, 256, 0, stream>>>(partial, nc);
    scan3_k<<<(M + 255) / 256, 256, 0, stream>>>(rp, partial, M);
    scatter_k<<<ehb, 256, 0, stream>>>(src, dst, adj, rp, rank, ent, cidx, EH);

    // ---- bf16 table + acc init ----
    cvt_k<<<(Nn * 32 + 255) / 256, 256, 0, stream>>>(user_emb, item_emb, tabA, NU, Nn);
    int selBlocks = (4 * (BU + BI) + 255) / 256;
    acc_init_k<<<selBlocks, 256, 0, stream>>>(user_emb, item_emb, users, items, acc,
                                              BU, BI, NU);

    int rowBlocksU = (4 * NU + 255) / 256;
    int rowBlocksN = (4 * Nn + 255) / 256;
    u32* cur = tabA;
    u32* nxt = tabB;
    for (int layer = 0; layer < 3; ++layer) {
        hipMemsetAsync(rowsum + NU, 0, sizeof(float) * (size_t)NI, stream);
        node_norms_k<<<rowBlocksN, 256, 0, stream>>>(cur, norms, Nn);
        cos_row_k<<<rowBlocksU, 256, 0, stream>>>(cur, norms, rp, ent, cosc, rowsum, NU);
        if (layer < 2) {
            spmm_fused_k<<<rowBlocksN, 256, 0, stream>>>(cur, rp, ent, cidx, cosc,
                                                         rowsum, Wp, bp, memc,
                                                         layer == 0 ? 1 : 0, nxt,
                                                         NU, EH, Nn);
            acc_upd_k<<<selBlocks, 256, 0, stream>>>(nxt, users, items, acc, BU, BI, NU);
            u32* t = cur; cur = nxt; nxt = t;
        } else {
            sel_spmm_k<<<selBlocks, 256, 0, stream>>>(cur, rp, ent, cidx, cosc, rowsum,
                                                      Wp, bp, memc, users, items,
                                                      acc, BU, BI, NU, EH);
        }
    }

    dim3 grid(BI / 64, BU / 64);
    final_gemm_k<<<grid, 256, 0, stream>>>(acc, (float*)d_out, BU, BI);
}